// Round 1
// baseline (52196.802 us; speedup 1.0000x reference)
//
#include <hip/hip_runtime.h>

// ---------------------------------------------------------------------------
// Speller (LAS decoder) on MI355X.
// Strategy: one persistent 256-block kernel runs all 300 decode steps with
// custom grid barriers (5/step). Prologue kernels build bf16 weights with
// permuted gate layout and the fused [keys2|vals] = enc @ [Wk@Wq^T | Wv]
// tensor (131 MB bf16 -> L3-resident).
// ---------------------------------------------------------------------------

typedef __attribute__((ext_vector_type(8))) short s8bf;   // 8 bf16 (4 VGPRs)
typedef __attribute__((ext_vector_type(4))) float f32x4;

#define NBLK 256
#define SCALE_E 0.044194173824159216f   // 1/sqrt(512)

struct Ptrs {
  const float* enc; const int* elen; const int* y;
  const float* emb;
  const float* Wih0; const float* Whh0; const float* bih0; const float* bhh0;
  const float* Wih1; const float* Whh1; const float* bih1; const float* bhh1;
  const float* Wq; const float* Wk; const float* Wv;
  const float* Wout; const float* bout; const float* bchar;
  unsigned short* kv;     // [64000][1024] bf16: [0,512) keys2 (Wq folded), [512,1024) vals
  unsigned short* W0p;    // [2048][1536] bf16, gate-permuted rows (4d+gate)
  unsigned short* W1p;    // [2048][1024] bf16, gate-permuted
  unsigned short* Wob;    // [512][1024] bf16 (W_out as-is)
  unsigned short* WkvT;   // [1024][512] bf16: row n = B[:,n]^T for kv prologue GEMM
  unsigned short* embbf;  // [31][512] bf16
  float* b0p; float* b1p; // [2048] permuted summed biases
  unsigned short* in0;    // [2][64][1536]  (emb | ctx | h0) double-buffered
  unsigned short* in1;    // [2][64][1024]  (h0 | h1)       double-buffered
  unsigned short* h1b;    // [64][512] bf16 h1 of current step
  unsigned short* hidb;   // [64][512] bf16 hid of current step
  float* c0s; float* c1s; // [64][512] fp32 cell states
  float* ctxa;            // [64][512] fp32 ctx accumulator (atomicAdd)
  float* ebuf;            // [64][1024] unnormalized exp(e)
  float* sbuf;            // [64] softmax denominators
  int* bars;              // [4096] one-shot barrier counters (zeroed in k_init)
  float* out;             // d_out: [64][300][31] logits then [64][300][1000] attn
};

__device__ __forceinline__ unsigned short f2bf(float f) {
  unsigned u = __float_as_uint(f);
  u += 0x7fffu + ((u >> 16) & 1u);          // RNE
  return (unsigned short)(u >> 16);
}
__device__ __forceinline__ float bf2f(unsigned short h) {
  return __uint_as_float(((unsigned)h) << 16);
}
__device__ __forceinline__ float sigm(float x) { return 1.f / (1.f + __expf(-x)); }

// grid barrier: one-shot counter per event, release/acquire at agent scope
__device__ __forceinline__ void gbar(int* bars, int idx, int nb) {
  __syncthreads();
  if (threadIdx.x == 0) {
    __builtin_amdgcn_fence(__ATOMIC_RELEASE, "agent");
    __hip_atomic_fetch_add(bars + idx, 1, __ATOMIC_RELAXED, __HIP_MEMORY_SCOPE_AGENT);
    while (__hip_atomic_load(bars + idx, __ATOMIC_RELAXED, __HIP_MEMORY_SCOPE_AGENT) < nb)
      __builtin_amdgcn_s_sleep(2);
    __builtin_amdgcn_fence(__ATOMIC_ACQUIRE, "agent");
  }
  __syncthreads();
}

// ---------------------------------------------------------------------------
// k_init: zero barriers/states, build step-0 input vector (emb(SOS)|0|0)
// ---------------------------------------------------------------------------
__global__ void k_init(Ptrs P) {
  int g = blockIdx.x * 256 + threadIdx.x;            // 65536 threads
  for (int i = g; i < 4096; i += 65536) P.bars[i] = 0;
  for (int i = g; i < 32768; i += 65536) { P.c0s[i] = 0.f; P.c1s[i] = 0.f; }
  for (int i = g; i < 65536; i += 65536) P.in1[i] = 0; // buffer 0 of in1
  for (int i = g; i < 98304; i += 65536) {            // buffer 0 of in0
    int b = i / 1536, d = i - b * 1536; (void)b;
    unsigned short v = 0;
    if (d < 512) v = f2bf(P.emb[d]);                  // SOS = row 0
    P.in0[i] = v;
  }
}

// ---------------------------------------------------------------------------
// k_prep: bf16 weight conversion + gate permutation + Wk@Wq^T fold
// grid 256 x 256
// ---------------------------------------------------------------------------
__global__ void k_prep(Ptrs P) {
  int bid = blockIdx.x, tid = threadIdx.x;
  // LSTM weights, permuted rows: gp -> orig row r = (gp&3)*512 + (gp>>2)
  for (int ri = 0; ri < 8; ++ri) {
    int gp = bid * 8 + ri;
    int r = (gp & 3) * 512 + (gp >> 2);
    for (int k = tid; k < 1536; k += 256)
      P.W0p[(size_t)gp * 1536 + k] =
          f2bf(k < 1024 ? P.Wih0[(size_t)r * 1024 + k] : P.Whh0[(size_t)r * 512 + (k - 1024)]);
    for (int k = tid; k < 1024; k += 256)
      P.W1p[(size_t)gp * 1024 + k] =
          f2bf(k < 512 ? P.Wih1[(size_t)r * 512 + k] : P.Whh1[(size_t)r * 512 + (k - 512)]);
    if (tid == 0) {
      P.b0p[gp] = P.bih0[r] + P.bhh0[r];
      P.b1p[gp] = P.bih1[r] + P.bhh1[r];
    }
  }
  // W_out (already [512][1024] row-major = cdn layout [h1|ctx])
  for (int ri = 0; ri < 2; ++ri) {
    int n = bid * 2 + ri;
    for (int k = tid; k < 1024; k += 256)
      P.Wob[(size_t)n * 1024 + k] = f2bf(P.Wout[(size_t)n * 1024 + k]);
  }
  // embedding bf16
  {
    int g = bid * 256 + tid;
    if (g < 31 * 512) P.embbf[g] = f2bf(P.emb[g]);
  }
  // WkvT: row n<512 -> M1[k][n] = sum_j Wk[k][j]*Wq[n][j]; row n>=512 -> Wv[k][n-512]
  for (int ri = 0; ri < 4; ++ri) {
    int n = bid * 4 + ri;
    if (n < 512) {
      const float* wq = P.Wq + (size_t)n * 512;
      for (int k = tid; k < 512; k += 256) {
        const float* wk = P.Wk + (size_t)k * 512;
        float s = 0.f;
        for (int j = 0; j < 512; ++j) s = fmaf(wk[j], wq[j], s);
        P.WkvT[(size_t)n * 512 + k] = f2bf(s);
      }
    } else {
      for (int k = tid; k < 512; k += 256)
        P.WkvT[(size_t)n * 512 + k] = f2bf(P.Wv[(size_t)k * 512 + (n - 512)]);
    }
  }
}

// ---------------------------------------------------------------------------
// k_kv: kv[m][n] = enc[m][:] @ WkvT[n][:]   (M=64000, N=1024, K=512, bf16 MFMA)
// grid 256 x 1024; wave = one 16-row m-strip, loops 64 n-tiles with A reuse.
// ---------------------------------------------------------------------------
__global__ __launch_bounds__(1024) void k_kv(Ptrs P) {
  int bid = blockIdx.x, tid = threadIdx.x;
  int w = tid >> 6, ln = tid & 63;
  __shared__ unsigned short lds2[16][16][16];
  int mt = bid * 16 + w;                       // 0..4095, valid < 4000 (block-uniform)
  bool valid = mt < 4000;
  s8bf afr[16];
  if (valid) {
    const float* ar = P.enc + (size_t)(mt * 16 + (ln & 15)) * 512 + ((ln >> 4) * 8);
    for (int ks = 0; ks < 16; ++ks) {
      const float* p = ar + ks * 32;
      s8bf a;
      for (int j = 0; j < 8; ++j) a[j] = (short)f2bf(p[j]);
      afr[ks] = a;
    }
  }
  for (int nt = 0; nt < 64; ++nt) {
    if (valid) {
      f32x4 acc = {0.f, 0.f, 0.f, 0.f};
      const unsigned short* br = P.WkvT + (size_t)(nt * 16 + (ln & 15)) * 512 + ((ln >> 4) * 8);
      for (int ks = 0; ks < 16; ++ks) {
        s8bf b = *(const s8bf*)(br + ks * 32);
        acc = __builtin_amdgcn_mfma_f32_16x16x32_bf16(afr[ks], b, acc, 0, 0, 0);
      }
      for (int r = 0; r < 4; ++r)
        lds2[w][(ln >> 4) * 4 + r][ln & 15] = f2bf(acc[r]);
    }
    __syncthreads();
    if (valid && ln < 32) {
      int row = ln >> 1, half = ln & 1;
      s8bf v = *(const s8bf*)&lds2[w][row][half * 8];
      *(s8bf*)(P.kv + (size_t)(mt * 16 + row) * 1024 + nt * 16 + half * 8) = v;
    }
    __syncthreads();
  }
}

// ---------------------------------------------------------------------------
// LSTM phase (blocks 0..31): gates = in @ Wp^T + bp (MFMA, permuted gates),
// fused pointwise cell update, h written (bf16) to two destinations.
// ---------------------------------------------------------------------------
__device__ __forceinline__ void lstm_phase(
    int bid, int tid, float (*lds_g)[16][16],
    const unsigned short* inbuf, int kdim, int ksteps,
    const unsigned short* Wp, const float* bp, float* cs,
    unsigned short* hdst0, int hstride0, int hoff0,
    unsigned short* hdst1, int hstride1, int hoff1) {
  if (bid >= 32) return;
  int w = tid >> 6, ln = tid & 63;
  int mt = w & 3, nt = bid * 4 + (w >> 2);
  const unsigned short* ar = inbuf + (size_t)(mt * 16 + (ln & 15)) * kdim + ((ln >> 4) * 8);
  const unsigned short* br = Wp + (size_t)(nt * 16 + (ln & 15)) * kdim + ((ln >> 4) * 8);
  f32x4 acc = {0.f, 0.f, 0.f, 0.f};
  for (int ks = 0; ks < ksteps; ++ks) {
    s8bf a = *(const s8bf*)(ar + ks * 32);
    s8bf b = *(const s8bf*)(br + ks * 32);
    acc = __builtin_amdgcn_mfma_f32_16x16x32_bf16(a, b, acc, 0, 0, 0);
  }
  float bias = bp[nt * 16 + (ln & 15)];
  for (int r = 0; r < 4; ++r)
    lds_g[w][(ln >> 4) * 4 + r][ln & 15] = acc[r] + bias;
  __syncthreads();
  int rb = ln >> 2, c = ln & 3;
  float gi = lds_g[w][rb][4 * c + 0];
  float gf = lds_g[w][rb][4 * c + 1];
  float gg = lds_g[w][rb][4 * c + 2];
  float go = lds_g[w][rb][4 * c + 3];
  int b = mt * 16 + rb, d = nt * 4 + c;
  float co = cs[b * 512 + d];
  float cn = fmaf(sigm(gf), co, sigm(gi) * tanhf(gg));
  float h = sigm(go) * tanhf(cn);
  cs[b * 512 + d] = cn;
  unsigned short hb = f2bf(h);
  hdst0[(size_t)b * hstride0 + hoff0 + d] = hb;
  hdst1[(size_t)b * hstride1 + hoff1 + d] = hb;
}

// ---------------------------------------------------------------------------
// logits + optional argmax->emb write (blocks 64..71, waves 0..7: one b each)
// ---------------------------------------------------------------------------
__device__ __forceinline__ void g_logits(int bid, int tid, const Ptrs& P, int tstep,
                                         unsigned short* embdst) {
  int w = tid >> 6, ln = tid & 63;
  if (bid < 64 || bid >= 72 || w >= 8) return;
  int b = (bid - 64) * 8 + w;
  float hv[8];
  s8bf hh = *(const s8bf*)(P.hidb + (size_t)b * 512 + ln * 8);
  for (int j = 0; j < 8; ++j) hv[j] = bf2f((unsigned short)hh[j]);
  float mx = -3.4e38f; int am = 0;
  for (int v = 0; v < 31; ++v) {
    s8bf ee = *(const s8bf*)(P.embbf + (size_t)v * 512 + ln * 8);
    float p = 0.f;
    for (int j = 0; j < 8; ++j) p = fmaf(bf2f((unsigned short)ee[j]), hv[j], p);
    for (int off = 32; off; off >>= 1) p += __shfl_down(p, off);
    if (ln == 0) {
      float lg = p + P.bchar[v];
      P.out[(size_t)b * 9300 + (size_t)tstep * 31 + v] = lg;
      if (lg > mx) { mx = lg; am = v; }   // first max wins on ties
    }
  }
  if (embdst) {
    am = __shfl(am, 0);
    *(s8bf*)(embdst + (size_t)b * 1536 + ln * 8) =
        *(const s8bf*)(P.embbf + (size_t)am * 512 + ln * 8);
  }
}

// ---------------------------------------------------------------------------
// k_main: persistent decode loop, 5 grid barriers / step
// ---------------------------------------------------------------------------
__global__ __launch_bounds__(1024) void k_main(Ptrs P) {
  __shared__ float lds_g[16][16][16];   // 16 KB GEMM tile buffer
  __shared__ float lds_ctx[16][512];    // 32 KB ctx reduction
  __shared__ float lds_s[16];
  int bid = blockIdx.x, tid = threadIdx.x;
  int w = tid >> 6, ln = tid & 63;
  int bi = 0;

  for (int t = 0; t < 300; ++t) {
    int par = t & 1, nxt = par ^ 1;
    const unsigned short* in0c = P.in0 + (size_t)par * 64 * 1536;
    unsigned short* in0n = P.in0 + (size_t)nxt * 64 * 1536;
    const unsigned short* in1c = P.in1 + (size_t)par * 64 * 1024;
    unsigned short* in1n = P.in1 + (size_t)nxt * 64 * 1024;

    // -- Phase A: LSTM0 (+ logits of step t-1 on spare blocks) --------------
    lstm_phase(bid, tid, lds_g, in0c, 1536, 48, P.W0p, P.b0p, P.c0s,
               in0n, 1536, 1024, (unsigned short*)in1c, 1024, 0);
    if (t > 0 && t != 299) g_logits(bid, tid, P, t - 1, nullptr);
    gbar(P.bars, bi++, NBLK);

    // -- Phase B: LSTM1; block 32 zeroes softmax denominators ---------------
    lstm_phase(bid, tid, lds_g, in1c, 1024, 32, P.W1p, P.b1p, P.c1s,
               in1n, 1024, 512, P.h1b, 512, 0);
    if (bid == 32 && tid < 64) P.sbuf[tid] = 0.f;
    gbar(P.bars, bi++, NBLK);

    // -- Phase D: e = h1 . keys2, exp, partial sums; zero ctx accumulator ---
    {
      int b = bid >> 2, ch = bid & 3;
      float h1r[8];
      s8bf hh = *(const s8bf*)(P.h1b + (size_t)b * 512 + ln * 8);
      for (int j = 0; j < 8; ++j) h1r[j] = bf2f((unsigned short)hh[j]);
      int len = P.elen[b];
      float wsum = 0.f;
      int t0 = ch * 250;
      for (int tt = t0 + w; tt < t0 + 250; tt += 16) {
        s8bf kk = *(const s8bf*)(P.kv + (size_t)(b * 1000 + tt) * 1024 + ln * 8);
        float p = 0.f;
        for (int j = 0; j < 8; ++j) p = fmaf(bf2f((unsigned short)kk[j]), h1r[j], p);
        for (int off = 32; off; off >>= 1) p += __shfl_down(p, off);
        if (ln == 0) {
          float pe = (tt < len) ? __expf(p * SCALE_E) : 0.f;  // |e| small: no max-sub needed
          P.ebuf[b * 1024 + tt] = pe;
          wsum += pe;
        }
      }
      if (ln == 0) lds_s[w] = wsum;
      __syncthreads();
      if (tid == 0) {
        float s = 0.f;
        for (int i = 0; i < 16; ++i) s += lds_s[i];
        unsafeAtomicAdd(&P.sbuf[b], s);
      }
      if (tid < 128) P.ctxa[bid * 128 + tid] = 0.f;
    }
    gbar(P.bars, bi++, NBLK);

    // -- Phase E: normalize, write attention_plot, partial ctx --------------
    {
      int b = bid >> 2, ch = bid & 3;
      float inv = 1.f / P.sbuf[b];
      float acc[8] = {0.f, 0.f, 0.f, 0.f, 0.f, 0.f, 0.f, 0.f};
      int t0 = ch * 250;
      size_t ob = 595200 + (size_t)b * 300000 + (size_t)t * 1000;
      for (int tt = t0 + w; tt < t0 + 250; tt += 16) {
        float ww = P.ebuf[b * 1024 + tt] * inv;
        if (ln == 0) P.out[ob + tt] = ww;
        s8bf vv = *(const s8bf*)(P.kv + (size_t)(b * 1000 + tt) * 1024 + 512 + ln * 8);
        for (int j = 0; j < 8; ++j) acc[j] = fmaf(bf2f((unsigned short)vv[j]), ww, acc[j]);
      }
      for (int j = 0; j < 8; ++j) lds_ctx[w][ln * 8 + j] = acc[j];
      __syncthreads();
      if (tid < 512) {
        float s = 0.f;
        for (int i = 0; i < 16; ++i) s += lds_ctx[i][tid];
        unsafeAtomicAdd(&P.ctxa[b * 512 + tid], s);
      }
    }
    gbar(P.bars, bi++, NBLK);

    // -- Phase F: hid = relu([h1|ctx]@Wout^T + bout); ctx/emb -> next in0 ---
    if (bid < 32) {
      int nt = bid, mt = w & 3, kq = w >> 2;
      f32x4 acc = {0.f, 0.f, 0.f, 0.f};
      const unsigned short* br = P.Wob + (size_t)(nt * 16 + (ln & 15)) * 1024 + kq * 256 + ((ln >> 4) * 8);
      int arow = mt * 16 + (ln & 15);
      if (kq < 2) {
        const unsigned short* ap = P.h1b + (size_t)arow * 512 + kq * 256 + ((ln >> 4) * 8);
        for (int ks = 0; ks < 8; ++ks) {
          s8bf a = *(const s8bf*)(ap + ks * 32);
          s8bf b8 = *(const s8bf*)(br + ks * 32);
          acc = __builtin_amdgcn_mfma_f32_16x16x32_bf16(a, b8, acc, 0, 0, 0);
        }
      } else {
        const float* ap = P.ctxa + (size_t)arow * 512 + (kq - 2) * 256 + ((ln >> 4) * 8);
        for (int ks = 0; ks < 8; ++ks) {
          s8bf a;
          for (int j = 0; j < 8; ++j) a[j] = (short)f2bf(ap[ks * 32 + j]);
          s8bf b8 = *(const s8bf*)(br + ks * 32);
          acc = __builtin_amdgcn_mfma_f32_16x16x32_bf16(a, b8, acc, 0, 0, 0);
        }
      }
      for (int r = 0; r < 4; ++r) lds_g[w][(ln >> 4) * 4 + r][ln & 15] = acc[r];
      __syncthreads();
      int mtp = tid >> 8, rb = (tid >> 4) & 15, cc = tid & 15;
      float hsum = lds_g[mtp][rb][cc] + lds_g[4 + mtp][rb][cc] +
                   lds_g[8 + mtp][rb][cc] + lds_g[12 + mtp][rb][cc];
      hsum += P.bout[nt * 16 + cc];
      hsum = fmaxf(hsum, 0.f);
      P.hidb[(size_t)(mtp * 16 + rb) * 512 + nt * 16 + cc] = f2bf(hsum);
    } else if (bid < 64) {
      int idx = (bid - 32) * 1024 + tid, b = idx >> 9, d = idx & 511;
      in0n[(size_t)b * 1536 + 512 + d] = f2bf(P.ctxa[b * 512 + d]);
    } else if (bid < 96) {
      if (t < 298) {   // teacher forcing: emb(y[:,t+1]); t=298 handled below
        int idx = (bid - 64) * 1024 + tid, b = idx >> 9, d = idx & 511;
        int sym = P.y[b * 300 + t + 1];
        in0n[(size_t)b * 1536 + d] = P.embbf[(size_t)sym * 512 + d];
      }
    }
    gbar(P.bars, bi++, NBLK);

    // -- step 298 only: logits_298 + argmax -> emb input of step 299 --------
    if (t == 298) {
      g_logits(bid, tid, P, 298, in0n);
      gbar(P.bars, bi++, NBLK);
    }
  }
  // final logits of step 299
  g_logits(bid, tid, P, 299, nullptr);
}

// ---------------------------------------------------------------------------
extern "C" void kernel_launch(void* const* d_in, const int* in_sizes, int n_in,
                              void* d_out, int out_size, void* d_ws, size_t ws_size,
                              hipStream_t stream) {
  (void)in_sizes; (void)n_in; (void)out_size; (void)ws_size;
  Ptrs P;
  P.enc   = (const float*)d_in[0];
  P.elen  = (const int*)d_in[1];
  P.y     = (const int*)d_in[2];
  P.emb   = (const float*)d_in[3];
  P.Wih0  = (const float*)d_in[4];
  P.Whh0  = (const float*)d_in[5];
  P.bih0  = (const float*)d_in[6];
  P.bhh0  = (const float*)d_in[7];
  P.Wih1  = (const float*)d_in[8];
  P.Whh1  = (const float*)d_in[9];
  P.bih1  = (const float*)d_in[10];
  P.bhh1  = (const float*)d_in[11];
  P.Wq    = (const float*)d_in[12];
  P.Wk    = (const float*)d_in[13];
  P.Wv    = (const float*)d_in[14];
  P.Wout  = (const float*)d_in[15];
  P.bout  = (const float*)d_in[16];
  P.bchar = (const float*)d_in[17];
  P.out   = (float*)d_out;

  char* ws = (char*)d_ws;
  size_t o = 0;
  auto alloc = [&](size_t n) { char* p = ws + o; o = (o + n + 255) & ~(size_t)255; return p; };
  P.kv    = (unsigned short*)alloc(64000ull * 1024 * 2);   // 131 MB
  P.W0p   = (unsigned short*)alloc(2048ull * 1536 * 2);
  P.W1p   = (unsigned short*)alloc(2048ull * 1024 * 2);
  P.Wob   = (unsigned short*)alloc(512ull * 1024 * 2);
  P.WkvT  = (unsigned short*)alloc(1024ull * 512 * 2);
  P.embbf = (unsigned short*)alloc(31ull * 512 * 2);
  P.b0p   = (float*)alloc(2048 * 4);
  P.b1p   = (float*)alloc(2048 * 4);
  P.in0   = (unsigned short*)alloc(2ull * 64 * 1536 * 2);
  P.in1   = (unsigned short*)alloc(2ull * 64 * 1024 * 2);
  P.h1b   = (unsigned short*)alloc(64ull * 512 * 2);
  P.hidb  = (unsigned short*)alloc(64ull * 512 * 2);
  P.c0s   = (float*)alloc(64ull * 512 * 4);
  P.c1s   = (float*)alloc(64ull * 512 * 4);
  P.ctxa  = (float*)alloc(64ull * 512 * 4);
  P.ebuf  = (float*)alloc(64ull * 1024 * 4);
  P.sbuf  = (float*)alloc(64 * 4);
  P.bars  = (int*)alloc(4096 * 4);
  // total ~145.2 MB of d_ws

  k_init<<<dim3(256), dim3(256), 0, stream>>>(P);
  k_prep<<<dim3(256), dim3(256), 0, stream>>>(P);
  k_kv<<<dim3(256), dim3(1024), 0, stream>>>(P);
  k_main<<<dim3(256), dim3(1024), 0, stream>>>(P);  // 256 blocks = 1/CU, co-resident
}

// Round 2
// 39234.900 us; speedup vs baseline: 1.3304x; 1.3304x over previous
//
#include <hip/hip_runtime.h>

// ---------------------------------------------------------------------------
// Speller (LAS decoder) on MI355X — round 2.
// Changes vs round 1:
//  * contention-free grid barrier (packed arrival slots + replicated release
//    lines) — round 1's single-line atomic barrier cost ~25 us x 1500.
//  * 3 barriers/step instead of 5: attention D+E fused into one kv sweep
//    (unnormalized ctx accumulation), hid-GEMM/logits pipelined into the
//    next step's phases on spare blocks.
//  * kv sweep clipped to encoder_len (~45% less kv traffic).
// ---------------------------------------------------------------------------

typedef __attribute__((ext_vector_type(8))) short s8bf;   // 8 bf16 (4 VGPRs)
typedef __attribute__((ext_vector_type(4))) float f32x4;

#define NBLK 256
#define SCALE_E 0.044194173824159216f   // 1/sqrt(512)

struct Ptrs {
  const float* enc; const int* elen; const int* y;
  const float* emb;
  const float* Wih0; const float* Whh0; const float* bih0; const float* bhh0;
  const float* Wih1; const float* Whh1; const float* bih1; const float* bhh1;
  const float* Wq; const float* Wk; const float* Wv;
  const float* Wout; const float* bout; const float* bchar;
  unsigned short* kv;     // [64000][1024] bf16: [0,512) keys2 (Wq folded), [512,1024) vals
  unsigned short* W0p;    // [2048][1536] bf16, gate-permuted rows (4d+gate)
  unsigned short* W1p;    // [2048][1024] bf16, gate-permuted
  unsigned short* Wob;    // [512][1024] bf16 (W_out as-is)
  unsigned short* WkvT;   // [1024][512] bf16
  unsigned short* embbf;  // [31][512] bf16
  float* b0p; float* b1p; // [2048] permuted summed biases
  unsigned short* h0b;    // [2][64][512] bf16, parity t&1
  unsigned short* h1b;    // [2][64][512] bf16, parity t&1
  unsigned short* hidb;   // [64][512] bf16, hid of step t-1 (written in A(t))
  unsigned short* embsel; // [64][512] bf16, emb(argmax(logits_298))
  float* c0s; float* c1s; // [64][512] fp32 cell states
  float* ctxa;            // [2][64][512] unnormalized ctx accumulator
  float* ebuf;            // [2][64][1024] unnormalized exp(e) (tails stay 0)
  float* sbuf;            // [2][64] softmax denominators
  int* barArr;            // [256] packed arrival epochs
  int* barRel;            // [256*16] replicated release epochs (64B/block)
  float* out;             // d_out: [64][300][31] logits then [64][300][1000] attn
};

__device__ __forceinline__ unsigned short f2bf(float f) {
  unsigned u = __float_as_uint(f);
  u += 0x7fffu + ((u >> 16) & 1u);          // RNE
  return (unsigned short)(u >> 16);
}
__device__ __forceinline__ float bf2f(unsigned short h) {
  return __uint_as_float(((unsigned)h) << 16);
}
__device__ __forceinline__ float sigm(float x) { return 1.f / (1.f + __expf(-x)); }

// ---------------------------------------------------------------------------
// Contention-free grid barrier. Arrivals: packed int slots (4 lines total,
// block-0 wave 0 polls all 256 with one coalesced dwordx4 load). Release:
// one 64B line PER BLOCK, so each poller spins on a private line.
// Epoch is monotonic -> no slot reset, no reuse hazard.
// ---------------------------------------------------------------------------
__device__ __forceinline__ void gbar(const Ptrs& P, int epoch) {
  __syncthreads();
  int bid = blockIdx.x, tid = threadIdx.x;
  if (tid == 0)
    __hip_atomic_store(P.barArr + bid, epoch, __ATOMIC_RELEASE, __HIP_MEMORY_SCOPE_AGENT);
  if (bid == 0) {
    if (tid < 64) {
      const int* base = P.barArr + tid * 4;
      for (;;) {
        int v0 = __hip_atomic_load(base + 0, __ATOMIC_RELAXED, __HIP_MEMORY_SCOPE_AGENT);
        int v1 = __hip_atomic_load(base + 1, __ATOMIC_RELAXED, __HIP_MEMORY_SCOPE_AGENT);
        int v2 = __hip_atomic_load(base + 2, __ATOMIC_RELAXED, __HIP_MEMORY_SCOPE_AGENT);
        int v3 = __hip_atomic_load(base + 3, __ATOMIC_RELAXED, __HIP_MEMORY_SCOPE_AGENT);
        int ok = (v0 >= epoch) && (v1 >= epoch) && (v2 >= epoch) && (v3 >= epoch);
        if (__all(ok)) break;
        __builtin_amdgcn_s_sleep(2);
      }
      __builtin_amdgcn_fence(__ATOMIC_ACQUIRE, "agent");
      for (int j = 0; j < 4; ++j)
        __hip_atomic_store(P.barRel + (tid * 4 + j) * 16, epoch,
                           __ATOMIC_RELEASE, __HIP_MEMORY_SCOPE_AGENT);
    }
    __syncthreads();
  } else {
    if (tid == 0) {
      while (__hip_atomic_load(P.barRel + bid * 16, __ATOMIC_RELAXED,
                               __HIP_MEMORY_SCOPE_AGENT) < epoch)
        __builtin_amdgcn_s_sleep(2);
      __builtin_amdgcn_fence(__ATOMIC_ACQUIRE, "agent");
    }
    __syncthreads();
  }
}

// ---------------------------------------------------------------------------
// k_init: zero barrier slots, cell states, parity-1 h buffers, ctx/exp bufs
// ---------------------------------------------------------------------------
__global__ void k_init(Ptrs P) {
  int g = blockIdx.x * 256 + threadIdx.x;            // 65536 threads
  if (g < 256) P.barArr[g] = 0;
  for (int i = g; i < 4096; i += 65536) P.barRel[i] = 0;
  for (int i = g; i < 32768; i += 65536) { P.c0s[i] = 0.f; P.c1s[i] = 0.f; }
  for (int i = g; i < 65536; i += 65536) {
    P.h0b[i] = 0; P.h1b[i] = 0; P.ctxa[i] = 0.f;
  }
  for (int i = g; i < 131072; i += 65536) P.ebuf[i] = 0.f;
  if (g < 128) P.sbuf[g] = 0.f;
}

// ---------------------------------------------------------------------------
// k_prep: bf16 weight conversion + gate permutation + Wk@Wq^T fold
// ---------------------------------------------------------------------------
__global__ void k_prep(Ptrs P) {
  int bid = blockIdx.x, tid = threadIdx.x;
  for (int ri = 0; ri < 8; ++ri) {
    int gp = bid * 8 + ri;
    int r = (gp & 3) * 512 + (gp >> 2);
    for (int k = tid; k < 1536; k += 256)
      P.W0p[(size_t)gp * 1536 + k] =
          f2bf(k < 1024 ? P.Wih0[(size_t)r * 1024 + k] : P.Whh0[(size_t)r * 512 + (k - 1024)]);
    for (int k = tid; k < 1024; k += 256)
      P.W1p[(size_t)gp * 1024 + k] =
          f2bf(k < 512 ? P.Wih1[(size_t)r * 512 + k] : P.Whh1[(size_t)r * 512 + (k - 512)]);
    if (tid == 0) {
      P.b0p[gp] = P.bih0[r] + P.bhh0[r];
      P.b1p[gp] = P.bih1[r] + P.bhh1[r];
    }
  }
  for (int ri = 0; ri < 2; ++ri) {
    int n = bid * 2 + ri;
    for (int k = tid; k < 1024; k += 256)
      P.Wob[(size_t)n * 1024 + k] = f2bf(P.Wout[(size_t)n * 1024 + k]);
  }
  {
    int g = bid * 256 + tid;
    if (g < 31 * 512) P.embbf[g] = f2bf(P.emb[g]);
  }
  for (int ri = 0; ri < 4; ++ri) {
    int n = bid * 4 + ri;
    if (n < 512) {
      const float* wq = P.Wq + (size_t)n * 512;
      for (int k = tid; k < 512; k += 256) {
        const float* wk = P.Wk + (size_t)k * 512;
        float s0 = 0.f, s1 = 0.f, s2 = 0.f, s3 = 0.f;
        for (int j = 0; j < 512; j += 4) {
          f32x4 a = *(const f32x4*)(wk + j);
          f32x4 b = *(const f32x4*)(wq + j);
          s0 = fmaf(a[0], b[0], s0); s1 = fmaf(a[1], b[1], s1);
          s2 = fmaf(a[2], b[2], s2); s3 = fmaf(a[3], b[3], s3);
        }
        P.WkvT[(size_t)n * 512 + k] = f2bf((s0 + s1) + (s2 + s3));
      }
    } else {
      for (int k = tid; k < 512; k += 256)
        P.WkvT[(size_t)n * 512 + k] = f2bf(P.Wv[(size_t)k * 512 + (n - 512)]);
    }
  }
}

// ---------------------------------------------------------------------------
// k_kv: kv[m][n] = enc[m][:] @ WkvT[n][:]  (M=64000, N=1024, K=512)
// ---------------------------------------------------------------------------
__global__ __launch_bounds__(1024) void k_kv(Ptrs P) {
  int bid = blockIdx.x, tid = threadIdx.x;
  int w = tid >> 6, ln = tid & 63;
  __shared__ unsigned short lds2[16][16][16];
  int mt = bid * 16 + w;
  bool valid = mt < 4000;
  s8bf afr[16];
  if (valid) {
    const float* ar = P.enc + (size_t)(mt * 16 + (ln & 15)) * 512 + ((ln >> 4) * 8);
    for (int ks = 0; ks < 16; ++ks) {
      f32x4 v0 = *(const f32x4*)(ar + ks * 32);
      f32x4 v1 = *(const f32x4*)(ar + ks * 32 + 4);
      s8bf a;
      a[0] = (short)f2bf(v0[0]); a[1] = (short)f2bf(v0[1]);
      a[2] = (short)f2bf(v0[2]); a[3] = (short)f2bf(v0[3]);
      a[4] = (short)f2bf(v1[0]); a[5] = (short)f2bf(v1[1]);
      a[6] = (short)f2bf(v1[2]); a[7] = (short)f2bf(v1[3]);
      afr[ks] = a;
    }
  }
  for (int nt = 0; nt < 64; ++nt) {
    if (valid) {
      f32x4 acc = {0.f, 0.f, 0.f, 0.f};
      const unsigned short* br = P.WkvT + (size_t)(nt * 16 + (ln & 15)) * 512 + ((ln >> 4) * 8);
      for (int ks = 0; ks < 16; ++ks) {
        s8bf b = *(const s8bf*)(br + ks * 32);
        acc = __builtin_amdgcn_mfma_f32_16x16x32_bf16(afr[ks], b, acc, 0, 0, 0);
      }
      for (int r = 0; r < 4; ++r)
        lds2[w][(ln >> 4) * 4 + r][ln & 15] = f2bf(acc[r]);
    }
    __syncthreads();
    if (valid && ln < 32) {
      int row = ln >> 1, half = ln & 1;
      s8bf v = *(const s8bf*)&lds2[w][row][half * 8];
      *(s8bf*)(P.kv + (size_t)(mt * 16 + row) * 1024 + nt * 16 + half * 8) = v;
    }
    __syncthreads();
  }
}

// ---------------------------------------------------------------------------
// Phase helpers for k_main
// ---------------------------------------------------------------------------
// LSTM0: gates = [emb|ctx(t-1)|h0(t-1)] @ W0p^T; blocks 0..31
__device__ __forceinline__ void lstm0_phase(int bid, int tid, int t, const Ptrs& P,
                                            float (*lds_g)[16][16]) {
  int w = tid >> 6, ln = tid & 63;
  int mt = w & 3, nt = bid * 4 + (w >> 2);
  int brow = mt * 16 + (ln & 15), koff = (ln >> 4) * 8;
  int cur = t & 1, prv = cur ^ 1;
  const unsigned short* bp = P.W0p + (size_t)(nt * 16 + (ln & 15)) * 1536 + koff;
  const unsigned short* embrow;
  if (t == 299) {
    embrow = P.embsel + (size_t)brow * 512 + koff;
  } else {
    int sym = (t == 0) ? 0 : P.y[brow * 300 + t];
    embrow = P.embbf + (size_t)sym * 512 + koff;
  }
  f32x4 acc = {0.f, 0.f, 0.f, 0.f};
  for (int ks = 0; ks < 16; ++ks) {
    s8bf af = *(const s8bf*)(embrow + ks * 32);
    s8bf bf8 = *(const s8bf*)(bp + ks * 32);
    acc = __builtin_amdgcn_mfma_f32_16x16x32_bf16(af, bf8, acc, 0, 0, 0);
  }
  if (t > 0) {
    float inv = 1.f / P.sbuf[prv * 64 + brow];
    const float* cp = P.ctxa + prv * 32768 + (size_t)brow * 512 + koff;
    for (int ks = 0; ks < 16; ++ks) {
      f32x4 v0 = *(const f32x4*)(cp + ks * 32);
      f32x4 v1 = *(const f32x4*)(cp + ks * 32 + 4);
      s8bf af;
      af[0] = (short)f2bf(v0[0] * inv); af[1] = (short)f2bf(v0[1] * inv);
      af[2] = (short)f2bf(v0[2] * inv); af[3] = (short)f2bf(v0[3] * inv);
      af[4] = (short)f2bf(v1[0] * inv); af[5] = (short)f2bf(v1[1] * inv);
      af[6] = (short)f2bf(v1[2] * inv); af[7] = (short)f2bf(v1[3] * inv);
      s8bf bf8 = *(const s8bf*)(bp + 512 + ks * 32);
      acc = __builtin_amdgcn_mfma_f32_16x16x32_bf16(af, bf8, acc, 0, 0, 0);
    }
  }
  const unsigned short* hp = P.h0b + prv * 32768 + (size_t)brow * 512 + koff;
  for (int ks = 0; ks < 16; ++ks) {
    s8bf af = *(const s8bf*)(hp + ks * 32);
    s8bf bf8 = *(const s8bf*)(bp + 1024 + ks * 32);
    acc = __builtin_amdgcn_mfma_f32_16x16x32_bf16(af, bf8, acc, 0, 0, 0);
  }
  float bias = P.b0p[nt * 16 + (ln & 15)];
  for (int r = 0; r < 4; ++r)
    lds_g[w][(ln >> 4) * 4 + r][ln & 15] = acc[r] + bias;
  __syncthreads();
  int rb = ln >> 2, c = ln & 3;
  float gi = lds_g[w][rb][4 * c + 0];
  float gf = lds_g[w][rb][4 * c + 1];
  float gg = lds_g[w][rb][4 * c + 2];
  float go = lds_g[w][rb][4 * c + 3];
  int bb = mt * 16 + rb, d = nt * 4 + c;
  float co = P.c0s[bb * 512 + d];
  float cn = fmaf(sigm(gf), co, sigm(gi) * tanhf(gg));
  float h = sigm(go) * tanhf(cn);
  P.c0s[bb * 512 + d] = cn;
  P.h0b[cur * 32768 + bb * 512 + d] = f2bf(h);
}

// LSTM1: gates = [h0(t)|h1(t-1)] @ W1p^T; blocks 0..31
__device__ __forceinline__ void lstm1_phase(int bid, int tid, int t, const Ptrs& P,
                                            float (*lds_g)[16][16]) {
  int w = tid >> 6, ln = tid & 63;
  int mt = w & 3, nt = bid * 4 + (w >> 2);
  int brow = mt * 16 + (ln & 15), koff = (ln >> 4) * 8;
  int cur = t & 1, prv = cur ^ 1;
  const unsigned short* bp = P.W1p + (size_t)(nt * 16 + (ln & 15)) * 1024 + koff;
  const unsigned short* h0p = P.h0b + cur * 32768 + (size_t)brow * 512 + koff;
  const unsigned short* h1p = P.h1b + prv * 32768 + (size_t)brow * 512 + koff;
  f32x4 acc = {0.f, 0.f, 0.f, 0.f};
  for (int ks = 0; ks < 16; ++ks) {
    s8bf af = *(const s8bf*)(h0p + ks * 32);
    s8bf bf8 = *(const s8bf*)(bp + ks * 32);
    acc = __builtin_amdgcn_mfma_f32_16x16x32_bf16(af, bf8, acc, 0, 0, 0);
  }
  for (int ks = 0; ks < 16; ++ks) {
    s8bf af = *(const s8bf*)(h1p + ks * 32);
    s8bf bf8 = *(const s8bf*)(bp + 512 + ks * 32);
    acc = __builtin_amdgcn_mfma_f32_16x16x32_bf16(af, bf8, acc, 0, 0, 0);
  }
  float bias = P.b1p[nt * 16 + (ln & 15)];
  for (int r = 0; r < 4; ++r)
    lds_g[w][(ln >> 4) * 4 + r][ln & 15] = acc[r] + bias;
  __syncthreads();
  int rb = ln >> 2, c = ln & 3;
  float gi = lds_g[w][rb][4 * c + 0];
  float gf = lds_g[w][rb][4 * c + 1];
  float gg = lds_g[w][rb][4 * c + 2];
  float go = lds_g[w][rb][4 * c + 3];
  int bb = mt * 16 + rb, d = nt * 4 + c;
  float co = P.c1s[bb * 512 + d];
  float cn = fmaf(sigm(gf), co, sigm(gi) * tanhf(gg));
  float h = sigm(go) * tanhf(cn);
  P.c1s[bb * 512 + d] = cn;
  P.h1b[cur * 32768 + bb * 512 + d] = f2bf(h);
}

// hid(s) = relu([h1(s)|ctx(s)] @ Wout^T + bout); blocks 32..47
__device__ __forceinline__ void hid_phase(int bid, int tid, int s, const Ptrs& P,
                                          float (*lds_g)[16][16]) {
  int w = tid >> 6, ln = tid & 63;
  int nl = w >> 3, kq = (w >> 2) & 1, mt = w & 3;
  int nt = (bid - 32) * 2 + nl;
  int brow = mt * 16 + (ln & 15), koff = (ln >> 4) * 8;
  int par = s & 1;
  const unsigned short* bp = P.Wob + (size_t)(nt * 16 + (ln & 15)) * 1024 + kq * 512 + koff;
  f32x4 acc = {0.f, 0.f, 0.f, 0.f};
  if (kq == 0) {
    const unsigned short* ap = P.h1b + par * 32768 + (size_t)brow * 512 + koff;
    for (int ks = 0; ks < 16; ++ks) {
      s8bf af = *(const s8bf*)(ap + ks * 32);
      s8bf bf8 = *(const s8bf*)(bp + ks * 32);
      acc = __builtin_amdgcn_mfma_f32_16x16x32_bf16(af, bf8, acc, 0, 0, 0);
    }
  } else {
    float inv = 1.f / P.sbuf[par * 64 + brow];
    const float* ap = P.ctxa + par * 32768 + (size_t)brow * 512 + koff;
    for (int ks = 0; ks < 16; ++ks) {
      f32x4 v0 = *(const f32x4*)(ap + ks * 32);
      f32x4 v1 = *(const f32x4*)(ap + ks * 32 + 4);
      s8bf af;
      af[0] = (short)f2bf(v0[0] * inv); af[1] = (short)f2bf(v0[1] * inv);
      af[2] = (short)f2bf(v0[2] * inv); af[3] = (short)f2bf(v0[3] * inv);
      af[4] = (short)f2bf(v1[0] * inv); af[5] = (short)f2bf(v1[1] * inv);
      af[6] = (short)f2bf(v1[2] * inv); af[7] = (short)f2bf(v1[3] * inv);
      s8bf bf8 = *(const s8bf*)(bp + ks * 32);
      acc = __builtin_amdgcn_mfma_f32_16x16x32_bf16(af, bf8, acc, 0, 0, 0);
    }
  }
  for (int r = 0; r < 4; ++r)
    lds_g[w][(ln >> 4) * 4 + r][ln & 15] = acc[r];
  __syncthreads();
  for (int r = 0; r < 2; ++r) {
    int idx = r * 1024 + tid;
    int tile = idx >> 8;                 // 0..7: nl2 = tile>>2, mt2 = tile&3
    int nl2 = tile >> 2, mt2 = tile & 3;
    int rb = (idx >> 4) & 15, cc = idx & 15;
    float hsum = lds_g[nl2 * 8 + mt2][rb][cc] + lds_g[nl2 * 8 + 4 + mt2][rb][cc];
    int ntg = (bid - 32) * 2 + nl2;
    hsum += P.bout[ntg * 16 + cc];
    hsum = fmaxf(hsum, 0.f);
    P.hidb[(size_t)(mt2 * 16 + rb) * 512 + ntg * 16 + cc] = f2bf(hsum);
  }
}

// logits(s) from hidb; blocks 32..39, waves 0..7 (one b per wave)
__device__ __forceinline__ void logits_phase(int bid, int tid, int s, const Ptrs& P,
                                             bool do_argmax) {
  int w = tid >> 6, ln = tid & 63;
  if (w >= 8) return;
  int b = (bid - 32) * 8 + w;
  float hv[8];
  s8bf hh = *(const s8bf*)(P.hidb + (size_t)b * 512 + ln * 8);
  for (int j = 0; j < 8; ++j) hv[j] = bf2f((unsigned short)hh[j]);
  float mx = -3.4e38f; int am = 0;
  for (int v = 0; v < 31; ++v) {
    s8bf ee = *(const s8bf*)(P.embbf + (size_t)v * 512 + ln * 8);
    float p = 0.f;
    for (int j = 0; j < 8; ++j) p = fmaf(bf2f((unsigned short)ee[j]), hv[j], p);
    for (int off = 32; off; off >>= 1) p += __shfl_down(p, off);
    if (ln == 0) {
      float lg = p + P.bchar[v];
      P.out[(size_t)b * 9300 + (size_t)s * 31 + v] = lg;
      if (lg > mx) { mx = lg; am = v; }
    }
  }
  if (do_argmax) {
    am = __shfl(am, 0);
    *(s8bf*)(P.embsel + (size_t)b * 512 + ln * 8) =
        *(const s8bf*)(P.embbf + (size_t)am * 512 + ln * 8);
  }
}

// attention-plot normalize+write for step s; blocks 48..63
__device__ __forceinline__ void attnnorm_phase(int bid, int tid, int s, const Ptrs& P) {
  int idx = (bid - 48) * 1024 + tid;
  if (idx >= 16000) return;
  int b = idx / 250, r = idx - b * 250;
  int par = s & 1;
  float inv = 1.f / P.sbuf[par * 64 + b];
  f32x4 v = *(const f32x4*)(P.ebuf + par * 65536 + b * 1024 + r * 4);
  v[0] *= inv; v[1] *= inv; v[2] *= inv; v[3] *= inv;
  *(f32x4*)(P.out + 595200 + (size_t)b * 300000 + (size_t)s * 1000 + r * 4) = v;
}

// zero ctxa/sbuf parity t for the upcoming sweep; blocks 40..47
__device__ __forceinline__ void zero_phase(int bid, int tid, int t, const Ptrs& P) {
  int idx = (bid - 40) * 1024 + tid;                 // 0..8191
  f32x4 z = {0.f, 0.f, 0.f, 0.f};
  *(f32x4*)(P.ctxa + (t & 1) * 32768 + idx * 4) = z;
  if (bid == 40 && tid < 64) P.sbuf[(t & 1) * 64 + tid] = 0.f;
}

// fused attention sweep over kv (keys dot + exp + unnormalized ctx); all blocks
__device__ __forceinline__ void sweep(int bid, int tid, int t, const Ptrs& P,
                                      float (*lds_ctx)[512], float* lds_s) {
  int w = tid >> 6, ln = tid & 63;
  int b = bid >> 2, ch = bid & 3;
  int par = t & 1;
  int len = P.elen[b];
  int t0 = ch * 250;
  int lim = t0 + 250; if (len < lim) lim = len;
  float h1r[8];
  {
    s8bf hh = *(const s8bf*)(P.h1b + par * 32768 + (size_t)b * 512 + ln * 8);
    for (int j = 0; j < 8; ++j) h1r[j] = bf2f((unsigned short)hh[j]);
  }
  float acc[8] = {0.f, 0.f, 0.f, 0.f, 0.f, 0.f, 0.f, 0.f};
  float wsum = 0.f;
  float* eb = P.ebuf + par * 65536 + b * 1024;
  const unsigned short* kvb = P.kv + (size_t)b * 1000 * 1024;
  int tt = t0 + w;
  bool have = tt < lim;
  s8bf kk, vv;
  if (have) {
    const unsigned short* row = kvb + (size_t)tt * 1024 + ln * 8;
    kk = *(const s8bf*)(row);
    vv = *(const s8bf*)(row + 512);
  }
  while (have) {
    int ttn = tt + 16;
    bool haven = ttn < lim;
    s8bf kk2, vv2;
    if (haven) {                                  // prefetch next row
      const unsigned short* row = kvb + (size_t)ttn * 1024 + ln * 8;
      kk2 = *(const s8bf*)(row);
      vv2 = *(const s8bf*)(row + 512);
    }
    float p0 = 0.f, p1 = 0.f;
    for (int j = 0; j < 8; j += 2) {
      p0 = fmaf(bf2f((unsigned short)kk[j]), h1r[j], p0);
      p1 = fmaf(bf2f((unsigned short)kk[j + 1]), h1r[j + 1], p1);
    }
    float p = p0 + p1;
    p += __shfl_xor(p, 32); p += __shfl_xor(p, 16); p += __shfl_xor(p, 8);
    p += __shfl_xor(p, 4);  p += __shfl_xor(p, 2);  p += __shfl_xor(p, 1);
    float pe = __expf(p * SCALE_E);               // |e| small: no max-sub needed
    if (ln == 0) { eb[tt] = pe; wsum += pe; }
    for (int j = 0; j < 8; ++j)
      acc[j] = fmaf(bf2f((unsigned short)vv[j]), pe, acc[j]);
    kk = kk2; vv = vv2; tt = ttn; have = haven;
  }
  if (ln == 0) lds_s[w] = wsum;
  for (int j = 0; j < 8; ++j) lds_ctx[w][ln * 8 + j] = acc[j];
  __syncthreads();
  if (tid < 512) {
    float s = 0.f;
    for (int i = 0; i < 16; ++i) s += lds_ctx[i][tid];
    unsafeAtomicAdd(P.ctxa + par * 32768 + b * 512 + tid, s);
  }
  if (tid == 0) {
    float s = 0.f;
    for (int i = 0; i < 16; ++i) s += lds_s[i];
    unsafeAtomicAdd(P.sbuf + par * 64 + b, s);
  }
}

// ---------------------------------------------------------------------------
// k_main: persistent decode loop, 3 grid barriers / step
// ---------------------------------------------------------------------------
__global__ __launch_bounds__(1024) void k_main(Ptrs P) {
  __shared__ float lds_g[16][16][16];   // 16 KB GEMM tile buffer
  __shared__ float lds_ctx[16][512];    // 32 KB ctx reduction
  __shared__ float lds_s[16];
  int bid = blockIdx.x, tid = threadIdx.x;
  int ep = 0;

  for (int t = 0; t < 300; ++t) {
    // -- Phase A: LSTM0(t) | hid(t-1) | attn-norm(t-1) ----------------------
    if (bid < 32) lstm0_phase(bid, tid, t, P, lds_g);
    else if (bid < 48) { if (t > 0) hid_phase(bid, tid, t - 1, P, lds_g); }
    else if (bid < 64) { if (t > 0) attnnorm_phase(bid, tid, t - 1, P); }
    gbar(P, ++ep);

    // -- Phase B: LSTM1(t) | logits(t-1) | zero ctxa/sbuf parity t ----------
    if (bid < 32) lstm1_phase(bid, tid, t, P, lds_g);
    else if (bid < 40) { if (t > 0) logits_phase(bid, tid, t - 1, P, false); }
    else if (bid < 48) zero_phase(bid, tid, t, P);
    gbar(P, ++ep);

    // -- Phase C: fused attention sweep -------------------------------------
    sweep(bid, tid, t, P, lds_ctx, lds_s);
    gbar(P, ++ep);

    // -- step 298: need argmax(logits_298) as step-299 input -----------------
    if (t == 298) {
      if (bid >= 32 && bid < 48) hid_phase(bid, tid, 298, P, lds_g);
      gbar(P, ++ep);
      if (bid >= 32 && bid < 40) logits_phase(bid, tid, 298, P, true);
      gbar(P, ++ep);
    }
  }
  // tail: hid(299) + attn(299), then logits(299)
  if (bid >= 32 && bid < 48) hid_phase(bid, tid, 299, P, lds_g);
  else if (bid >= 48 && bid < 64) attnnorm_phase(bid, tid, 299, P);
  gbar(P, ++ep);
  if (bid >= 32 && bid < 40) logits_phase(bid, tid, 299, P, false);
}

// ---------------------------------------------------------------------------
extern "C" void kernel_launch(void* const* d_in, const int* in_sizes, int n_in,
                              void* d_out, int out_size, void* d_ws, size_t ws_size,
                              hipStream_t stream) {
  (void)in_sizes; (void)n_in; (void)out_size; (void)ws_size;
  Ptrs P;
  P.enc   = (const float*)d_in[0];
  P.elen  = (const int*)d_in[1];
  P.y     = (const int*)d_in[2];
  P.emb   = (const float*)d_in[3];
  P.Wih0  = (const float*)d_in[4];
  P.Whh0  = (const float*)d_in[5];
  P.bih0  = (const float*)d_in[6];
  P.bhh0  = (const float*)d_in[7];
  P.Wih1  = (const float*)d_in[8];
  P.Whh1  = (const float*)d_in[9];
  P.bih1  = (const float*)d_in[10];
  P.bhh1  = (const float*)d_in[11];
  P.Wq    = (const float*)d_in[12];
  P.Wk    = (const float*)d_in[13];
  P.Wv    = (const float*)d_in[14];
  P.Wout  = (const float*)d_in[15];
  P.bout  = (const float*)d_in[16];
  P.bchar = (const float*)d_in[17];
  P.out   = (float*)d_out;

  char* ws = (char*)d_ws;
  size_t o = 0;
  auto alloc = [&](size_t n) { char* p = ws + o; o = (o + n + 255) & ~(size_t)255; return p; };
  P.kv     = (unsigned short*)alloc(64000ull * 1024 * 2);   // 131 MB
  P.W0p    = (unsigned short*)alloc(2048ull * 1536 * 2);
  P.W1p    = (unsigned short*)alloc(2048ull * 1024 * 2);
  P.Wob    = (unsigned short*)alloc(512ull * 1024 * 2);
  P.WkvT   = (unsigned short*)alloc(1024ull * 512 * 2);
  P.embbf  = (unsigned short*)alloc(31ull * 512 * 2);
  P.b0p    = (float*)alloc(2048 * 4);
  P.b1p    = (float*)alloc(2048 * 4);
  P.h0b    = (unsigned short*)alloc(2ull * 64 * 512 * 2);
  P.h1b    = (unsigned short*)alloc(2ull * 64 * 512 * 2);
  P.hidb   = (unsigned short*)alloc(64ull * 512 * 2);
  P.embsel = (unsigned short*)alloc(64ull * 512 * 2);
  P.c0s    = (float*)alloc(64ull * 512 * 4);
  P.c1s    = (float*)alloc(64ull * 512 * 4);
  P.ctxa   = (float*)alloc(2ull * 64 * 512 * 4);
  P.ebuf   = (float*)alloc(2ull * 64 * 1024 * 4);
  P.sbuf   = (float*)alloc(2ull * 64 * 4);
  P.barArr = (int*)alloc(256 * 4);
  P.barRel = (int*)alloc(256 * 16 * 4);

  k_init<<<dim3(256), dim3(256), 0, stream>>>(P);
  k_prep<<<dim3(256), dim3(256), 0, stream>>>(P);
  k_kv<<<dim3(256), dim3(1024), 0, stream>>>(P);
  k_main<<<dim3(256), dim3(1024), 0, stream>>>(P);
}